// Round 1
// baseline (7674.518 us; speedup 1.0000x reference)
//
#include <hip/hip_runtime.h>
#include <math.h>

// Problem constants
#define BB 4
#define SS 32
#define CC 128
#define HH 32
#define WW 32
#define HIDN 128
#define CIN 256      // C + HID
#define PLANE 1024   // 32*32
#define LDSW 34      // 32 + 2 halo

// -------------------------------------------------------------------------
// Transpose conv_w [512][256][3][3] -> wt [ic][ky][kx][hc][gate] so that the
// 4 gate weights for a given (ic, tap, hc) are one contiguous float4.
// out idx = ((ic*9 + tap)*128 + hc)*4 + g
__global__ void transpose_w_kernel(const float* __restrict__ w, float* __restrict__ wt) {
    int idx = blockIdx.x * blockDim.x + threadIdx.x;
    if (idx >= CIN * 9 * 512) return;
    int g   = idx & 3;
    int hc  = (idx >> 2) & 127;
    int tap = (idx >> 9) % 9;
    int ic  = idx / (9 * 512);
    wt[idx] = w[((size_t)(g * 128 + hc) * CIN + ic) * 9 + tap];
}

// Broadcast learned init state over batch + spatial. Layout [B][HID][32*32].
__global__ void init_state_kernel(const float* __restrict__ ih, const float* __restrict__ icst,
                                  float* __restrict__ h0, float* __restrict__ c0) {
    int idx = blockIdx.x * blockDim.x + threadIdx.x;
    if (idx >= BB * HIDN * PLANE) return;
    int hid = (idx >> 10) & (HIDN - 1);
    h0[idx] = ih[hid];
    c0[idx] = icst[hid];
}

__device__ __forceinline__ float sigmoidf_(float v) { return 1.0f / (1.0f + __expf(-v)); }

// -------------------------------------------------------------------------
// One ConvLSTM step, fused: 3x3 conv over [x_t ; h_prev] (256 ch) -> 4 gates
// for ONE hid channel, full 32x32 spatial, + LSTM pointwise + spatial mean.
// grid = B*HID = 512 blocks, 256 threads, each thread owns a 2x2 patch.
__global__ __launch_bounds__(256, 2) void step_kernel(
    const float* __restrict__ x, const float* __restrict__ wt,
    const float* __restrict__ bias, const float* __restrict__ hprev,
    float* __restrict__ hnext, float* __restrict__ cst,
    float* __restrict__ feat, int t)
{
    __shared__ float lds[2][LDSW * LDSW];
    __shared__ float red[4];

    const int tid = threadIdx.x;
    const int b  = blockIdx.x >> 7;
    const int hc = blockIdx.x & 127;
    const int px = (tid & 15) * 2;
    const int py = (tid >> 4) * 2;

    // zero both LDS buffers (border stays 0 = SAME padding)
    for (int e = tid; e < 2 * LDSW * LDSW; e += 256) ((float*)lds)[e] = 0.0f;

    float acc[4][4];
    #pragma unroll
    for (int g = 0; g < 4; ++g) {
        float bv = bias[g * 128 + hc];
        #pragma unroll
        for (int p = 0; p < 4; ++p) acc[g][p] = bv;
    }

    const float* xbase = x + ((size_t)(b * SS + t) * CC) * PLANE;
    const float* hbase = hprev + ((size_t)b * HIDN) * PLANE;

    // stage plane ic=0 into buffer 0
    {
        #pragma unroll
        for (int k = 0; k < 4; ++k) {
            int e = tid + k * 256;
            int yy = e >> 5, xx = e & 31;
            lds[0][(yy + 1) * LDSW + xx + 1] = xbase[e];
        }
    }
    __syncthreads();

    for (int ic = 0; ic < CIN; ++ic) {
        // prefetch next plane global -> regs while computing current
        float r[4];
        if (ic + 1 < CIN) {
            const float* pb = (ic + 1 < CC) ? (xbase + (size_t)(ic + 1) * PLANE)
                                            : (hbase + (size_t)(ic + 1 - CC) * PLANE);
            #pragma unroll
            for (int k = 0; k < 4; ++k) r[k] = pb[tid + k * 256];
        }

        const float* Lb = lds[ic & 1];
        float v[4][4];
        #pragma unroll
        for (int dy = 0; dy < 4; ++dy)
            #pragma unroll
            for (int dx = 0; dx < 4; ++dx)
                v[dy][dx] = Lb[(py + dy) * LDSW + px + dx];

        #pragma unroll
        for (int ky = 0; ky < 3; ++ky)
        #pragma unroll
        for (int kx = 0; kx < 3; ++kx) {
            const float4 wg = *(const float4*)(wt + ((((size_t)ic * 3 + ky) * 3 + kx) * 128 + hc) * 4);
            #pragma unroll
            for (int p = 0; p < 4; ++p) {
                float val = v[(p >> 1) + ky][(p & 1) + kx];
                acc[0][p] = fmaf(wg.x, val, acc[0][p]);
                acc[1][p] = fmaf(wg.y, val, acc[1][p]);
                acc[2][p] = fmaf(wg.z, val, acc[2][p]);
                acc[3][p] = fmaf(wg.w, val, acc[3][p]);
            }
        }

        if (ic + 1 < CIN) {
            int bufn = (ic + 1) & 1;
            #pragma unroll
            for (int k = 0; k < 4; ++k) {
                int e = tid + k * 256;
                int yy = e >> 5, xx = e & 31;
                lds[bufn][(yy + 1) * LDSW + xx + 1] = r[k];
            }
        }
        __syncthreads();
    }

    // LSTM pointwise + pool accumulate
    float hsum = 0.0f;
    float* cbase = cst   + ((size_t)(b * HIDN + hc)) * PLANE;
    float* hnb   = hnext + ((size_t)(b * HIDN + hc)) * PLANE;
    #pragma unroll
    for (int p = 0; p < 4; ++p) {
        int yy = py + (p >> 1), xx = px + (p & 1);
        int pos = yy * 32 + xx;
        float iv = sigmoidf_(acc[0][p]);
        float fv = sigmoidf_(acc[1][p]);
        float ov = sigmoidf_(acc[2][p]);
        float gv = tanhf(acc[3][p]);
        float cp = cbase[pos];
        float cn = fmaf(fv, cp, iv * gv);
        float hn = ov * tanhf(cn);
        cbase[pos] = cn;
        hnb[pos]   = hn;
        hsum += hn;
    }

    // block reduction of hsum (256 threads = 4 waves)
    #pragma unroll
    for (int off = 32; off > 0; off >>= 1) hsum += __shfl_down(hsum, off, 64);
    if ((tid & 63) == 0) red[tid >> 6] = hsum;
    __syncthreads();
    if (tid == 0) {
        float s = red[0] + red[1] + red[2] + red[3];
        feat[(size_t)(b * SS + t) * HIDN + hc] = s * (1.0f / 1024.0f);
    }
}

// -------------------------------------------------------------------------
// Head: feat[b,s,:] -> relu(feat @ fc_w.T + fc_b) -> offset/angle scalars.
// grid = B*S = 128 blocks, 128 threads (one per output channel c).
__global__ __launch_bounds__(128) void head_kernel(
    const float* __restrict__ feat, const float* __restrict__ fcw,
    const float* __restrict__ fcb, const float* __restrict__ fcow,
    const float* __restrict__ fcob, const float* __restrict__ fcaw,
    const float* __restrict__ fcab, float* __restrict__ out)
{
    __shared__ float sf[128];
    __shared__ float redo[2], reda[2];
    int bs = blockIdx.x;
    int c  = threadIdx.x;
    sf[c] = feat[(size_t)bs * 128 + c];
    __syncthreads();
    float a = fcb[c];
    #pragma unroll 8
    for (int k = 0; k < 128; ++k) a = fmaf(fcw[c * 128 + k], sf[k], a);
    a = fmaxf(a, 0.0f);
    float po = a * fcow[c], pa = a * fcaw[c];
    #pragma unroll
    for (int off = 32; off > 0; off >>= 1) {
        po += __shfl_down(po, off, 64);
        pa += __shfl_down(pa, off, 64);
    }
    if ((c & 63) == 0) { redo[c >> 6] = po; reda[c >> 6] = pa; }
    __syncthreads();
    if (c == 0) {
        out[bs]       = redo[0] + redo[1] + fcob[0];
        out[128 + bs] = reda[0] + reda[1] + fcab[0];
    }
}

// -------------------------------------------------------------------------
extern "C" void kernel_launch(void* const* d_in, const int* in_sizes, int n_in,
                              void* d_out, int out_size, void* d_ws, size_t ws_size,
                              hipStream_t stream) {
    const float* x      = (const float*)d_in[0];
    const float* conv_w = (const float*)d_in[1];
    const float* conv_b = (const float*)d_in[2];
    const float* init_h = (const float*)d_in[3];
    const float* init_c = (const float*)d_in[4];
    const float* fc_w   = (const float*)d_in[5];
    const float* fc_b   = (const float*)d_in[6];
    const float* fco_w  = (const float*)d_in[7];
    const float* fco_b  = (const float*)d_in[8];
    const float* fca_w  = (const float*)d_in[9];
    const float* fca_b  = (const float*)d_in[10];

    float* ws   = (float*)d_ws;
    float* wt   = ws;                       // 256*9*512       = 1179648
    float* h0   = wt + 1179648;             // 4*128*1024      =  524288
    float* h1   = h0 + 524288;
    float* cst  = h1 + 524288;
    float* feat = cst + 524288;             // 4*32*128        =   16384

    transpose_w_kernel<<<(CIN * 9 * 512 + 255) / 256, 256, 0, stream>>>(conv_w, wt);
    init_state_kernel<<<(BB * HIDN * PLANE + 255) / 256, 256, 0, stream>>>(init_h, init_c, h0, cst);

    float* hb[2] = { h0, h1 };
    for (int t = 0; t < SS; ++t) {
        step_kernel<<<BB * HIDN, 256, 0, stream>>>(
            x, wt, conv_b, hb[t & 1], hb[(t + 1) & 1], cst, feat, t);
    }

    head_kernel<<<BB * SS, 128, 0, stream>>>(
        feat, fc_w, fc_b, fco_w, fco_b, fca_w, fca_b, (float*)d_out);
}

// Round 2
// 1136.661 us; speedup vs baseline: 6.7518x; 6.7518x over previous
//
#include <hip/hip_runtime.h>
#include <math.h>

#define BB 4
#define SS 32
#define CCH 128
#define HIDN 128
#define PLANE 1024
#define ZP 34
#define NOC 512
#define NIC 256

typedef _Float16 f16;
typedef _Float16 f16x8 __attribute__((ext_vector_type(8)));
typedef float f32x4 __attribute__((ext_vector_type(4)));

__device__ __forceinline__ float sigmoidf_(float v) { return 1.0f / (1.0f + __expf(-v)); }

__device__ __forceinline__ void gload16(const void* g, void* l) {
    __builtin_amdgcn_global_load_lds(
        (const __attribute__((address_space(1))) void*)g,
        (__attribute__((address_space(3))) void*)l, 16, 0, 0);
}

// ---------------------------------------------------------------------------
// Weight prep (once): conv_w [512][256][3][3] f32 -> wt [tap][oc'][ic] f16
// with oc' = hc*4 + g (gate-interleaved rows), src oc = g*128 + hc.
__global__ void wprep_kernel(const float* __restrict__ w, f16* __restrict__ wt) {
    int idx = blockIdx.x * 256 + threadIdx.x;
    if (idx >= 9 * 512 * 256) return;
    int ic  = idx & 255;
    int ocp = (idx >> 8) & 511;
    int tap = idx >> 17;
    int hc = ocp >> 2, g = ocp & 3;
    int oc = g * 128 + hc;
    wt[idx] = (f16)w[((size_t)(oc * 256 + ic)) * 9 + tap];
}

// ---------------------------------------------------------------------------
// Init: fill zpad (borders=0, x_0 ch<128, init_h ch>=128), c state, zero feat.
// grid = B*34 blocks, 256 threads (thread = channel).
__global__ __launch_bounds__(256) void init_kernel(
    const float* __restrict__ x, const float* __restrict__ ih,
    const float* __restrict__ icst, f16* __restrict__ zpad,
    float* __restrict__ cst, float* __restrict__ feat)
{
    int bx = blockIdx.x;
    int b = bx / 34, y = bx % 34;
    int ch = threadIdx.x;
    f16* zrow = zpad + (((size_t)b * ZP + y) * ZP) * NIC;
    bool border_y = (y == 0) | (y == 33);
    for (int xx = 0; xx < 34; ++xx) {
        float v;
        if (border_y || xx == 0 || xx == 33) v = 0.f;
        else if (ch < 128) v = x[((((size_t)b * SS + 0) * CCH + ch) * 32 + (y - 1)) * 32 + (xx - 1)];
        else v = ih[ch - 128];
        zrow[xx * NIC + ch] = (f16)v;
    }
    if (y >= 1 && y <= 32 && ch < 128) {
        float cv = icst[ch];
        for (int xx = 0; xx < 32; ++xx)
            cst[((size_t)b * PLANE + (y - 1) * 32 + xx) * 128 + ch] = cv;
    }
    if (y == 33) {
        for (int k = 0; k < 16; ++k) feat[(size_t)b * 4096 + ch + k * 256] = 0.f;
    }
}

// ---------------------------------------------------------------------------
// Conv as implicit GEMM via MFMA f16. grid = 512 blocks:
//   bid: mt(8) | nt(8) | b(4) | half(2).  BM=64 oc, BN=128 px, K=9taps*128ic.
// 4 waves = 2(M)x2(N), wave tile 32x64. LDS: A 36KB + Z 16KB, swizzled.
__global__ __launch_bounds__(256, 2) void conv_kernel(
    const f16* __restrict__ wt, const f16* __restrict__ zpad,
    float* __restrict__ gates)
{
    __shared__ unsigned char Ald[36864];   // [tap][64 oc][4 q][16B]
    __shared__ unsigned char Zld[16384];   // [204 px -> 1024 slots][16B]

    const int bid = blockIdx.x;
    const int mt = bid & 7;
    const int nt = (bid >> 3) & 7;
    const int b  = (bid >> 6) & 3;
    const int half = bid >> 8;
    const int icb = half * 128;
    const int tid = threadIdx.x;
    const int lane = tid & 63;
    const int wid = tid >> 6;
    const int wr = wid >> 1, wc = wid & 1;

    f32x4 acc[2][4];
    #pragma unroll
    for (int i = 0; i < 2; ++i)
        #pragma unroll
        for (int j = 0; j < 4; ++j) acc[i][j] = (f32x4){0.f, 0.f, 0.f, 0.f};

    const size_t zbase = ((size_t)b * ZP + nt * 4) * ZP * NIC;

    for (int icc = 0; icc < 4; ++icc) {
        const int ic0 = icb + icc * 32;
        // stage Z: 204 px * 4 qslots = 816 slots (padded to 1024)
        #pragma unroll
        for (int r = 0; r < 4; ++r) {
            int s = tid + r * 256;
            int p = s >> 2; if (p > 203) p = 203;
            int q = s & 3;
            int row = p / 34;
            int xx = p - row * 34;
            int qs = q ^ ((p >> 1) & 3);
            const f16* src = zpad + zbase + ((size_t)row * ZP + xx) * NIC + ic0 + qs * 8;
            gload16(src, Zld + s * 16);
        }
        // stage A: 9 taps * 64 oc * 4 q = 2304 slots
        #pragma unroll
        for (int r = 0; r < 9; ++r) {
            int sa = tid + r * 256;
            int tap = sa >> 8;
            int p = (sa >> 2) & 63;
            int q = sa & 3;
            int qs = q ^ ((p >> 1) & 3);
            const f16* src = wt + ((size_t)(tap * NOC + mt * 64 + p)) * NIC + ic0 + qs * 8;
            gload16(src, Ald + sa * 16);
        }
        __syncthreads();

        #pragma unroll
        for (int tap = 0; tap < 9; ++tap) {
            const int dy = tap / 3, dx = tap % 3;
            f16x8 af[2], bf[4];
            #pragma unroll
            for (int fm = 0; fm < 2; ++fm) {
                int p = wr * 32 + fm * 16 + (lane & 15);
                int q = lane >> 4;
                int byt = (tap * 64 + p) * 64 + ((q ^ ((p >> 1) & 3)) * 16);
                af[fm] = *(const f16x8*)(Ald + byt);
            }
            #pragma unroll
            for (int fn = 0; fn < 4; ++fn) {
                int n = wc * 64 + fn * 16;
                int ly = n >> 5, fx = (n >> 4) & 1;
                int p = (ly + dy) * 34 + fx * 16 + dx + (lane & 15);
                int q = lane >> 4;
                int byt = p * 64 + ((q ^ ((p >> 1) & 3)) * 16);
                bf[fn] = *(const f16x8*)(Zld + byt);
            }
            #pragma unroll
            for (int fm = 0; fm < 2; ++fm)
                #pragma unroll
                for (int fn = 0; fn < 4; ++fn)
                    acc[fm][fn] = __builtin_amdgcn_mfma_f32_16x16x32_f16(
                        af[fm], bf[fn], acc[fm][fn], 0, 0, 0);
        }
        __syncthreads();
    }

    float* gb = gates + ((size_t)half * BB + b) * PLANE * NOC;
    #pragma unroll
    for (int fm = 0; fm < 2; ++fm) {
        int oc = mt * 64 + wr * 32 + fm * 16 + ((lane >> 4) << 2);
        #pragma unroll
        for (int fn = 0; fn < 4; ++fn) {
            int px = nt * 128 + wc * 64 + fn * 16 + (lane & 15);
            *(f32x4*)(gb + (size_t)px * NOC + oc) = acc[fm][fn];
        }
    }
}

// ---------------------------------------------------------------------------
// LSTM pointwise + h->zpad(f16) + x_{t+1}->zpad(f16) + pooled-mean atomics.
// grid = B*32 blocks (b, row), 256 thr: hc = tid&127, sub = tid>>7 (x halves).
__global__ __launch_bounds__(256) void lstm_pw_kernel(
    const float* __restrict__ g0, const float* __restrict__ g1,
    const float* __restrict__ bias, const float* __restrict__ x,
    float* __restrict__ cst, f16* __restrict__ zpad,
    float* __restrict__ feat, int t)
{
    __shared__ float sm[256];
    const int tid = threadIdx.x;
    const int hc = tid & 127, sub = tid >> 7;
    const int b = blockIdx.x >> 5, row = blockIdx.x & 31;
    const float bi = bias[hc], bff = bias[128 + hc], bo = bias[256 + hc], bg = bias[384 + hc];
    float hsum = 0.f;
    #pragma unroll 4
    for (int i = 0; i < 16; ++i) {
        int xcol = sub * 16 + i;
        int px = row * 32 + xcol;
        size_t go = ((size_t)b * PLANE + px) * NOC + hc * 4;
        f32x4 ga = *(const f32x4*)(g0 + go);
        f32x4 gh = *(const f32x4*)(g1 + go);
        float iv = sigmoidf_(ga.x + gh.x + bi);
        float fv = sigmoidf_(ga.y + gh.y + bff);
        float ov = sigmoidf_(ga.z + gh.z + bo);
        float gv = tanhf(ga.w + gh.w + bg);
        size_t co = ((size_t)b * PLANE + px) * 128 + hc;
        float cp = cst[co];
        float cn = fv * cp + iv * gv;
        float hn = ov * tanhf(cn);
        cst[co] = cn;
        zpad[(((size_t)b * ZP + row + 1) * ZP + xcol + 1) * NIC + 128 + hc] = (f16)hn;
        hsum += hn;
    }
    if (t + 1 < SS) {
        const float* xs = x + ((((size_t)b * SS + (t + 1)) * CCH + hc) * 32 + row) * 32 + sub * 16;
        f16* zd = zpad + (((size_t)b * ZP + row + 1) * ZP + 1 + sub * 16) * NIC + hc;
        #pragma unroll 4
        for (int i = 0; i < 16; ++i) zd[i * NIC] = (f16)xs[i];
    }
    sm[tid] = hsum;
    __syncthreads();
    if (tid < 128)
        atomicAdd(feat + ((size_t)b * SS + t) * 128 + hc, (sm[tid] + sm[tid + 128]) * (1.f / 1024.f));
}

// ---------------------------------------------------------------------------
// Head (unchanged): feat -> relu(fc) -> offset/angle.
__global__ __launch_bounds__(128) void head_kernel(
    const float* __restrict__ feat, const float* __restrict__ fcw,
    const float* __restrict__ fcb, const float* __restrict__ fcow,
    const float* __restrict__ fcob, const float* __restrict__ fcaw,
    const float* __restrict__ fcab, float* __restrict__ out)
{
    __shared__ float sf[128];
    __shared__ float redo[2], reda[2];
    int bs = blockIdx.x;
    int c  = threadIdx.x;
    sf[c] = feat[(size_t)bs * 128 + c];
    __syncthreads();
    float a = fcb[c];
    #pragma unroll 8
    for (int k = 0; k < 128; ++k) a = fmaf(fcw[c * 128 + k], sf[k], a);
    a = fmaxf(a, 0.0f);
    float po = a * fcow[c], pa = a * fcaw[c];
    #pragma unroll
    for (int off = 32; off > 0; off >>= 1) {
        po += __shfl_down(po, off, 64);
        pa += __shfl_down(pa, off, 64);
    }
    if ((c & 63) == 0) { redo[c >> 6] = po; reda[c >> 6] = pa; }
    __syncthreads();
    if (c == 0) {
        out[bs]       = redo[0] + redo[1] + fcob[0];
        out[128 + bs] = reda[0] + reda[1] + fcab[0];
    }
}

// ---------------------------------------------------------------------------
extern "C" void kernel_launch(void* const* d_in, const int* in_sizes, int n_in,
                              void* d_out, int out_size, void* d_ws, size_t ws_size,
                              hipStream_t stream) {
    const float* x      = (const float*)d_in[0];
    const float* conv_w = (const float*)d_in[1];
    const float* conv_b = (const float*)d_in[2];
    const float* init_h = (const float*)d_in[3];
    const float* init_c = (const float*)d_in[4];
    const float* fc_w   = (const float*)d_in[5];
    const float* fc_b   = (const float*)d_in[6];
    const float* fco_w  = (const float*)d_in[7];
    const float* fco_b  = (const float*)d_in[8];
    const float* fca_w  = (const float*)d_in[9];
    const float* fca_b  = (const float*)d_in[10];

    unsigned char* wsb = (unsigned char*)d_ws;
    size_t off = 0;
    f16* wt = (f16*)(wsb + off);            off += (size_t)9 * 512 * 256 * 2;     // 2359296
    off = (off + 255) & ~(size_t)255;
    f16* zpad = (f16*)(wsb + off);          off += (size_t)BB * ZP * ZP * NIC * 2; // 2367488
    off = (off + 255) & ~(size_t)255;
    float* gates = (float*)(wsb + off);     off += (size_t)2 * BB * PLANE * NOC * 4; // 16777216
    off = (off + 255) & ~(size_t)255;
    float* cst = (float*)(wsb + off);       off += (size_t)BB * PLANE * 128 * 4;   // 2097152
    off = (off + 255) & ~(size_t)255;
    float* feat = (float*)(wsb + off);      off += (size_t)BB * SS * 128 * 4;      // 65536

    wprep_kernel<<<(9 * 512 * 256 + 255) / 256, 256, 0, stream>>>(conv_w, wt);
    init_kernel<<<BB * 34, 256, 0, stream>>>(x, init_h, init_c, zpad, cst, feat);

    const float* g0 = gates;
    const float* g1 = gates + (size_t)BB * PLANE * NOC;
    for (int t = 0; t < SS; ++t) {
        conv_kernel<<<512, 256, 0, stream>>>(wt, zpad, gates);
        lstm_pw_kernel<<<BB * 32, 256, 0, stream>>>(g0, g1, conv_b, x, cst, zpad, feat, t);
    }

    head_kernel<<<BB * SS, 128, 0, stream>>>(
        feat, fc_w, fc_b, fco_w, fco_b, fca_w, fca_b, (float*)d_out);
}

// Round 3
// 969.224 us; speedup vs baseline: 7.9182x; 1.1728x over previous
//
#include <hip/hip_runtime.h>
#include <math.h>

#define BB 4
#define SS 32
#define CCH 128
#define PLANE 1024
#define ZP 34
#define NOC 512
#define NIC 256

typedef _Float16 f16;
typedef _Float16 f16x8 __attribute__((ext_vector_type(8)));
typedef float f32x4 __attribute__((ext_vector_type(4)));

__device__ __forceinline__ float sigmoidf_(float v) { return 1.0f / (1.0f + __expf(-v)); }

__device__ __forceinline__ void gload16(const void* g, void* l) {
    __builtin_amdgcn_global_load_lds(
        (const __attribute__((address_space(1))) void*)g,
        (__attribute__((address_space(3))) void*)l, 16, 0, 0);
}

// ---------------------------------------------------------------------------
// Weight prep (once): conv_w [512][256][3][3] f32 -> wt [tap][oc'][ic] f16
// with oc' = hc*4 + g (gate-interleaved rows), src oc = g*128 + hc.
__global__ void wprep_kernel(const float* __restrict__ w, f16* __restrict__ wt) {
    int idx = blockIdx.x * 256 + threadIdx.x;
    if (idx >= 9 * 512 * 256) return;
    int ic  = idx & 255;
    int ocp = (idx >> 8) & 511;
    int tap = idx >> 17;
    int hc = ocp >> 2, g = ocp & 3;
    int oc = g * 128 + hc;
    wt[idx] = (f16)w[((size_t)(oc * 256 + ic)) * 9 + tap];
}

// ---------------------------------------------------------------------------
// Init: fill zpad (borders=0, x_0 ch<128, init_h ch>=128), c state, zero feat.
__global__ __launch_bounds__(256) void init_kernel(
    const float* __restrict__ x, const float* __restrict__ ih,
    const float* __restrict__ icst, f16* __restrict__ zpad,
    float* __restrict__ cst, float* __restrict__ feat)
{
    int bx = blockIdx.x;
    int b = bx / 34, y = bx % 34;
    int ch = threadIdx.x;
    f16* zrow = zpad + (((size_t)b * ZP + y) * ZP) * NIC;
    bool border_y = (y == 0) | (y == 33);
    for (int xx = 0; xx < 34; ++xx) {
        float v;
        if (border_y || xx == 0 || xx == 33) v = 0.f;
        else if (ch < 128) v = x[((((size_t)b * SS + 0) * CCH + ch) * 32 + (y - 1)) * 32 + (xx - 1)];
        else v = ih[ch - 128];
        zrow[xx * NIC + ch] = (f16)v;
    }
    if (y >= 1 && y <= 32 && ch < 128) {
        float cv = icst[ch];
        for (int xx = 0; xx < 32; ++xx)
            cst[((size_t)b * PLANE + (y - 1) * 32 + xx) * 128 + ch] = cv;
    }
    if (y == 33) {
        for (int k = 0; k < 16; ++k) feat[(size_t)b * 4096 + ch + k * 256] = 0.f;
    }
}

// ---------------------------------------------------------------------------
// Conv as implicit GEMM via MFMA f16, double-buffered staging, counted vmcnt.
// grid = 256 blocks: mt(8) | nt(4) | b(4) | half(2). Block: 64 oc x 256 px.
// 8 waves = 2(M) x 4(N), wave tile 32 x 64. K = 9 taps x 128 ic, chunk 32.
// LDS per buffer: A 2304 slots (36864B) + Z 1536 slots (24576B) = 61440B, x2.
__global__ __launch_bounds__(512, 1) void conv_kernel(
    const f16* __restrict__ wt, const f16* __restrict__ zpad,
    float* __restrict__ gates)
{
    __shared__ unsigned char LDS[2 * 61440];

    const int bid = blockIdx.x;
    const int mt = bid & 7;
    const int nt = (bid >> 3) & 3;
    const int b  = (bid >> 5) & 3;
    const int half = bid >> 7;
    const int tid = threadIdx.x;
    const int lane = tid & 63;
    const int wid = tid >> 6;
    const int wr = wid >> 2, wc = wid & 3;

    // --- precompute staging descriptors (8 rounds, 64 slots each, 60 chunks)
    const f16* srcb[8];
    int soff[8];
    #pragma unroll
    for (int r = 0; r < 8; ++r) {
        int c = wid + r * 8;
        int s = c * 64 + lane;
        if (c < 60) {
            if (s < 2304) {                        // A: [tap][64 oc][4 q]
                int tap = s >> 8, rem = s & 255;
                int p = rem >> 2, q = rem & 3;
                int qs = q ^ ((p >> 1) & 3);
                srcb[r] = wt + ((size_t)(tap * NOC + mt * 64 + p)) * NIC + qs * 8;
            } else {                               // Z: [384 px pad][4 q]
                int z = s - 2304;
                int p = z >> 2; if (p > 339) p = 339;
                int q = z & 3;
                int qs = q ^ ((p >> 1) & 3);
                int row = p / 34, xx = p - row * 34;
                srcb[r] = zpad + (((size_t)b * ZP + nt * 8 + row) * ZP + xx) * NIC + qs * 8;
            }
            soff[r] = s * 16;
        } else { srcb[r] = wt; soff[r] = 0; }
    }
    const int icbase = half * 128;

    f32x4 acc[2][4];
    #pragma unroll
    for (int i = 0; i < 2; ++i)
        #pragma unroll
        for (int j = 0; j < 4; ++j) acc[i][j] = (f32x4){0.f, 0.f, 0.f, 0.f};

    auto stage = [&](int bufsel, int icc) {
        int ico = icbase + icc * 32;
        #pragma unroll
        for (int r = 0; r < 8; ++r) {
            if (wid + r * 8 < 60)
                gload16(srcb[r] + ico, LDS + bufsel * 61440 + soff[r]);
        }
    };

    auto compute = [&](int bufsel) {
        const unsigned char* Ab = LDS + bufsel * 61440;
        const unsigned char* Zb = Ab + 36864;
        #pragma unroll
        for (int tap = 0; tap < 9; ++tap) {
            const int dy = tap / 3, dx = tap - dy * 3;
            f16x8 af[2], bf[4];
            #pragma unroll
            for (int fm = 0; fm < 2; ++fm) {
                int p = wr * 32 + fm * 16 + (lane & 15);
                int q = lane >> 4;
                af[fm] = *(const f16x8*)(Ab + (tap * 256 + p * 4 + (q ^ ((p >> 1) & 3))) * 16);
            }
            #pragma unroll
            for (int fn = 0; fn < 4; ++fn) {
                int n = wc * 64 + fn * 16 + (lane & 15);
                int p = ((n >> 5) + dy) * 34 + (n & 31) + dx;
                int q = lane >> 4;
                bf[fn] = *(const f16x8*)(Zb + (p * 4 + (q ^ ((p >> 1) & 3))) * 16);
            }
            #pragma unroll
            for (int fm = 0; fm < 2; ++fm)
                #pragma unroll
                for (int fn = 0; fn < 4; ++fn)
                    acc[fm][fn] = __builtin_amdgcn_mfma_f32_16x16x32_f16(
                        af[fm], bf[fn], acc[fm][fn], 0, 0, 0);
        }
    };

    stage(0, 0);
    #pragma unroll
    for (int icc = 0; icc < 4; ++icc) {
        if (icc < 3) stage((icc + 1) & 1, icc + 1);
        if (icc < 3) {
            if (wid < 4) asm volatile("s_waitcnt vmcnt(8)" ::: "memory");
            else         asm volatile("s_waitcnt vmcnt(7)" ::: "memory");
        } else {
            asm volatile("s_waitcnt vmcnt(0)" ::: "memory");
        }
        __builtin_amdgcn_s_barrier();
        asm volatile("" ::: "memory");
        compute(icc & 1);
        asm volatile("" ::: "memory");
        __builtin_amdgcn_s_barrier();
    }

    float* gb = gates + ((size_t)half * BB + b) * PLANE * NOC;
    #pragma unroll
    for (int fm = 0; fm < 2; ++fm) {
        int oc = mt * 64 + wr * 32 + fm * 16 + ((lane >> 4) << 2);
        #pragma unroll
        for (int fn = 0; fn < 4; ++fn) {
            int px = nt * 256 + wc * 64 + fn * 16 + (lane & 15);
            *(f32x4*)(gb + (size_t)px * NOC + oc) = acc[fm][fn];
        }
    }
}

// ---------------------------------------------------------------------------
// LSTM pointwise + h->zpad(f16) + x_{t+1}->zpad(f16) + pooled-mean atomics.
// grid = 256 blocks: bid = b(4) x row(32) x h2(2); 256 thr: hc=tid&127,
// sub=tid>>7; each thread handles 8 columns.
__global__ __launch_bounds__(256) void lstm_pw_kernel(
    const float* __restrict__ g0, const float* __restrict__ g1,
    const float* __restrict__ bias, const float* __restrict__ x,
    float* __restrict__ cst, f16* __restrict__ zpad,
    float* __restrict__ feat, int t)
{
    __shared__ float sm[256];
    const int tid = threadIdx.x;
    const int hc = tid & 127, sub = tid >> 7;
    const int bid = blockIdx.x;
    const int b = bid >> 6, row = (bid >> 1) & 31, h2 = bid & 1;
    const int colbase = h2 * 16 + sub * 8;
    const float bi = bias[hc], bff = bias[128 + hc], bo = bias[256 + hc], bg = bias[384 + hc];
    float hsum = 0.f;
    #pragma unroll 4
    for (int i = 0; i < 8; ++i) {
        int col = colbase + i;
        int px = row * 32 + col;
        size_t go = ((size_t)b * PLANE + px) * NOC + hc * 4;
        f32x4 ga = *(const f32x4*)(g0 + go);
        f32x4 gh = *(const f32x4*)(g1 + go);
        float iv = sigmoidf_(ga.x + gh.x + bi);
        float fv = sigmoidf_(ga.y + gh.y + bff);
        float ov = sigmoidf_(ga.z + gh.z + bo);
        float gv = tanhf(ga.w + gh.w + bg);
        size_t co = ((size_t)b * PLANE + px) * 128 + hc;
        float cp = cst[co];
        float cn = fv * cp + iv * gv;
        float hn = ov * tanhf(cn);
        cst[co] = cn;
        zpad[(((size_t)b * ZP + row + 1) * ZP + col + 1) * NIC + 128 + hc] = (f16)hn;
        hsum += hn;
    }
    if (t + 1 < SS) {
        const float* xs = x + ((((size_t)b * SS + (t + 1)) * CCH + hc) * 32 + row) * 32 + colbase;
        f16* zd = zpad + (((size_t)b * ZP + row + 1) * ZP + 1 + colbase) * NIC + hc;
        #pragma unroll 4
        for (int i = 0; i < 8; ++i) zd[i * NIC] = (f16)xs[i];
    }
    sm[tid] = hsum;
    __syncthreads();
    if (tid < 128)
        atomicAdd(feat + ((size_t)b * SS + t) * 128 + hc, (sm[tid] + sm[tid + 128]) * (1.f / 1024.f));
}

// ---------------------------------------------------------------------------
// Head: feat -> relu(fc) -> offset/angle.
__global__ __launch_bounds__(128) void head_kernel(
    const float* __restrict__ feat, const float* __restrict__ fcw,
    const float* __restrict__ fcb, const float* __restrict__ fcow,
    const float* __restrict__ fcob, const float* __restrict__ fcaw,
    const float* __restrict__ fcab, float* __restrict__ out)
{
    __shared__ float sf[128];
    __shared__ float redo[2], reda[2];
    int bs = blockIdx.x;
    int c  = threadIdx.x;
    sf[c] = feat[(size_t)bs * 128 + c];
    __syncthreads();
    float a = fcb[c];
    #pragma unroll 8
    for (int k = 0; k < 128; ++k) a = fmaf(fcw[c * 128 + k], sf[k], a);
    a = fmaxf(a, 0.0f);
    float po = a * fcow[c], pa = a * fcaw[c];
    #pragma unroll
    for (int off = 32; off > 0; off >>= 1) {
        po += __shfl_down(po, off, 64);
        pa += __shfl_down(pa, off, 64);
    }
    if ((c & 63) == 0) { redo[c >> 6] = po; reda[c >> 6] = pa; }
    __syncthreads();
    if (c == 0) {
        out[bs]       = redo[0] + redo[1] + fcob[0];
        out[128 + bs] = reda[0] + reda[1] + fcab[0];
    }
}

// ---------------------------------------------------------------------------
extern "C" void kernel_launch(void* const* d_in, const int* in_sizes, int n_in,
                              void* d_out, int out_size, void* d_ws, size_t ws_size,
                              hipStream_t stream) {
    const float* x      = (const float*)d_in[0];
    const float* conv_w = (const float*)d_in[1];
    const float* conv_b = (const float*)d_in[2];
    const float* init_h = (const float*)d_in[3];
    const float* init_c = (const float*)d_in[4];
    const float* fc_w   = (const float*)d_in[5];
    const float* fc_b   = (const float*)d_in[6];
    const float* fco_w  = (const float*)d_in[7];
    const float* fco_b  = (const float*)d_in[8];
    const float* fca_w  = (const float*)d_in[9];
    const float* fca_b  = (const float*)d_in[10];

    unsigned char* wsb = (unsigned char*)d_ws;
    size_t off = 0;
    f16* wt = (f16*)(wsb + off);            off += (size_t)9 * 512 * 256 * 2;
    off = (off + 255) & ~(size_t)255;
    f16* zpad = (f16*)(wsb + off);          off += (size_t)BB * ZP * ZP * NIC * 2;
    off = (off + 255) & ~(size_t)255;
    float* gates = (float*)(wsb + off);     off += (size_t)2 * BB * PLANE * NOC * 4;
    off = (off + 255) & ~(size_t)255;
    float* cst = (float*)(wsb + off);       off += (size_t)BB * PLANE * 128 * 4;
    off = (off + 255) & ~(size_t)255;
    float* feat = (float*)(wsb + off);      off += (size_t)BB * SS * 128 * 4;

    wprep_kernel<<<(9 * 512 * 256 + 255) / 256, 256, 0, stream>>>(conv_w, wt);
    init_kernel<<<BB * 34, 256, 0, stream>>>(x, init_h, init_c, zpad, cst, feat);

    const float* g0 = gates;
    const float* g1 = gates + (size_t)BB * PLANE * NOC;
    for (int t = 0; t < SS; ++t) {
        conv_kernel<<<256, 512, 0, stream>>>(wt, zpad, gates);
        lstm_pw_kernel<<<256, 256, 0, stream>>>(g0, g1, conv_b, x, cst, zpad, feat, t);
    }

    head_kernel<<<BB * SS, 128, 0, stream>>>(
        feat, fc_w, fc_b, fco_w, fco_b, fca_w, fca_b, (float*)d_out);
}

// Round 4
// 767.744 us; speedup vs baseline: 9.9962x; 1.2624x over previous
//
#include <hip/hip_runtime.h>
#include <math.h>

#define BB 4
#define SS 32
#define CCH 128
#define PLANE 1024
#define ZP 34
#define NOC 512
#define NIC 256

#define LDSA 18432            // A region: 1152 slots * 16B
#define LDSZ 21760            // Z region: 1360 slots * 16B
#define LDSB (LDSA + LDSZ)    // 40192 per buffer

typedef _Float16 f16;
typedef _Float16 f16x8 __attribute__((ext_vector_type(8)));
typedef float f32x4 __attribute__((ext_vector_type(4)));

__device__ __forceinline__ float sigmoidf_(float v) { return 1.0f / (1.0f + __expf(-v)); }

__device__ __forceinline__ void gload16(const void* g, void* l) {
    __builtin_amdgcn_global_load_lds(
        (const __attribute__((address_space(1))) void*)g,
        (__attribute__((address_space(3))) void*)l, 16, 0, 0);
}

// ---------------------------------------------------------------------------
// Weight prep (once): conv_w [512][256][3][3] f32 -> wt [tap][oc'][ic] f16
// with oc' = hc*4 + g (gate-interleaved rows), src oc = g*128 + hc.
__global__ void wprep_kernel(const float* __restrict__ w, f16* __restrict__ wt) {
    int idx = blockIdx.x * 256 + threadIdx.x;
    if (idx >= 9 * 512 * 256) return;
    int ic  = idx & 255;
    int ocp = (idx >> 8) & 511;
    int tap = idx >> 17;
    int hc = ocp >> 2, g = ocp & 3;
    int oc = g * 128 + hc;
    wt[idx] = (f16)w[((size_t)(oc * 256 + ic)) * 9 + tap];
}

// ---------------------------------------------------------------------------
// Init: zpad0 interior = [x_0 ; init_h], borders of BOTH zpad buffers = 0,
// cst[b][hc][px] = init_c[hc], feat = 0.  grid = B*34, 256 threads (= channel).
__global__ __launch_bounds__(256) void init_kernel(
    const float* __restrict__ x, const float* __restrict__ ih,
    const float* __restrict__ icst, f16* __restrict__ zpad0,
    f16* __restrict__ zpad1, float* __restrict__ cst, float* __restrict__ feat)
{
    int bx = blockIdx.x;
    int b = bx / 34, y = bx % 34;
    int ch = threadIdx.x;
    f16* z0row = zpad0 + (((size_t)b * ZP + y) * ZP) * NIC;
    f16* z1row = zpad1 + (((size_t)b * ZP + y) * ZP) * NIC;
    bool border_y = (y == 0) | (y == 33);
    for (int xx = 0; xx < 34; ++xx) {
        bool border = border_y || xx == 0 || xx == 33;
        float v;
        if (border) v = 0.f;
        else if (ch < 128) v = x[((((size_t)b * SS + 0) * CCH + ch) * 32 + (y - 1)) * 32 + (xx - 1)];
        else v = ih[ch - 128];
        z0row[xx * NIC + ch] = (f16)v;
        if (border) z1row[xx * NIC + ch] = (f16)0.f;
    }
    if (y >= 1 && y <= 32 && ch < 128) {
        float cv = icst[ch];
        float* cr = cst + ((size_t)b * 128 + ch) * PLANE + (y - 1) * 32;
        for (int xx = 0; xx < 32; ++xx) cr[xx] = cv;
    }
    if (y == 33) {
        for (int k = 0; k < 16; ++k) feat[(size_t)b * 4096 + ch + k * 256] = 0.f;
    }
}

// ---------------------------------------------------------------------------
// Fused ConvLSTM step: full-K implicit GEMM (K = 9 taps x 256 ic) + LSTM
// pointwise + h->znext + x_{t+1}->znext + pooled mean.
// grid = 256: mt(16) | nt(4) | b(4).  Block: 32 oc' x 256 px, 256 thr,
// 4 waves 1(M)x4(N), wave tile 32x64 (2 A-frags x 4 B-frags of 16x16x32).
__global__ __launch_bounds__(256) void step_kernel(
    const f16* __restrict__ wt, const f16* __restrict__ zread,
    f16* __restrict__ zwrite, const float* __restrict__ x,
    const float* __restrict__ bias, float* __restrict__ cst,
    float* __restrict__ feat, int t)
{
    __shared__ unsigned char LDS[2 * LDSB];   // 80384 B
    __shared__ float redbuf[4][8];

    const int bid = blockIdx.x;
    const int mt = bid & 15;
    const int nt = (bid >> 4) & 3;
    const int b  = bid >> 6;
    const int tid = threadIdx.x;
    const int lane = tid & 63;
    const int wc = tid >> 6;          // wave = N-column 0..3

    // --- staging descriptors: 2512 slots (A 1152 + Z 1360), 10 rounds
    const f16* srcb[10];
    int soff[10];
    #pragma unroll
    for (int r = 0; r < 10; ++r) {
        int s = tid + r * 256;
        if (s < 1152) {                       // A: [tap][32 oc'][4 q]
            int tap = s >> 7, rem = s & 127;
            int p = rem >> 2, q = rem & 3;
            int qs = q ^ ((p >> 1) & 3);
            srcb[r] = wt + ((size_t)(tap * NOC + mt * 32 + p)) * NIC + qs * 8;
        } else {                              // Z: [340 px][4 q]
            int z = s - 1152;
            int p = z >> 2; if (p > 339) p = 339;
            int q = z & 3;
            int qs = q ^ ((p >> 1) & 3);
            int row = p / 34, xx = p - row * 34;
            srcb[r] = zread + (((size_t)b * ZP + nt * 8 + row) * ZP + xx) * NIC + qs * 8;
        }
        soff[r] = s * 16;
    }

    f32x4 acc[2][4];
    #pragma unroll
    for (int i = 0; i < 2; ++i)
        #pragma unroll
        for (int j = 0; j < 4; ++j) acc[i][j] = (f32x4){0.f, 0.f, 0.f, 0.f};

    auto stage = [&](int bufsel, int icc) {
        int ico = icc * 32;
        #pragma unroll
        for (int r = 0; r < 10; ++r) {
            if (r < 9 || tid < 208)
                gload16(srcb[r] + ico, LDS + bufsel * LDSB + soff[r]);
        }
    };

    auto compute = [&](int bufsel) {
        const unsigned char* Ab = LDS + bufsel * LDSB;
        const unsigned char* Zb = Ab + LDSA;
        const int q = lane >> 4;
        #pragma unroll
        for (int tap = 0; tap < 9; ++tap) {
            const int dy = tap / 3, dx = tap - dy * 3;
            f16x8 af[2], bf[4];
            #pragma unroll
            for (int fm = 0; fm < 2; ++fm) {
                int p = fm * 16 + (lane & 15);
                af[fm] = *(const f16x8*)(Ab + (tap * 128 + p * 4 + (q ^ ((p >> 1) & 3))) * 16);
            }
            #pragma unroll
            for (int fn = 0; fn < 4; ++fn) {
                int n = wc * 64 + fn * 16 + (lane & 15);
                int p = ((n >> 5) + dy) * 34 + (n & 31) + dx;
                bf[fn] = *(const f16x8*)(Zb + (p * 4 + (q ^ ((p >> 1) & 3))) * 16);
            }
            #pragma unroll
            for (int fm = 0; fm < 2; ++fm)
                #pragma unroll
                for (int fn = 0; fn < 4; ++fn)
                    acc[fm][fn] = __builtin_amdgcn_mfma_f32_16x16x32_f16(
                        af[fm], bf[fn], acc[fm][fn], 0, 0, 0);
        }
    };

    stage(0, 0);
    #pragma unroll
    for (int icc = 0; icc < 8; ++icc) {
        if (icc < 7) stage((icc + 1) & 1, icc + 1);
        if (icc < 7) asm volatile("s_waitcnt vmcnt(10)" ::: "memory");
        else         asm volatile("s_waitcnt vmcnt(0)" ::: "memory");
        __builtin_amdgcn_s_barrier();
        asm volatile("" ::: "memory");
        compute(icc & 1);
        asm volatile("" ::: "memory");
        __builtin_amdgcn_s_barrier();
    }

    // ---- fused LSTM pointwise epilogue (lane holds i,f,o,g in acc.xyzw) ----
    const int q4 = lane >> 4;
    const int pxl = lane & 15;
    float psum[2];
    #pragma unroll
    for (int fm = 0; fm < 2; ++fm) {
        const int hc = mt * 8 + fm * 4 + q4;
        const float bi = bias[hc], bff = bias[128 + hc];
        const float bo = bias[256 + hc], bg = bias[384 + hc];
        psum[fm] = 0.f;
        #pragma unroll
        for (int fn = 0; fn < 4; ++fn) {
            int px = nt * 256 + wc * 64 + fn * 16 + pxl;
            f32x4 a = acc[fm][fn];
            float iv = sigmoidf_(a.x + bi);
            float fv = sigmoidf_(a.y + bff);
            float ov = sigmoidf_(a.z + bo);
            float gv = tanhf(a.w + bg);
            size_t co = ((size_t)b * 128 + hc) * PLANE + px;
            float cp = cst[co];
            float cn = fv * cp + iv * gv;
            float hn = ov * tanhf(cn);
            cst[co] = cn;
            int row = px >> 5, col = px & 31;
            zwrite[(((size_t)b * ZP + row + 1) * ZP + col + 1) * NIC + 128 + hc] = (f16)hn;
            psum[fm] += hn;
        }
    }
    #pragma unroll
    for (int m = 1; m < 16; m <<= 1) {
        psum[0] += __shfl_xor(psum[0], m, 64);
        psum[1] += __shfl_xor(psum[1], m, 64);
    }
    if (pxl == 0) {
        redbuf[wc][q4]     = psum[0];
        redbuf[wc][4 + q4] = psum[1];
    }

    // ---- stage x_{t+1} into znext (interior channels 0..127) ----
    if (t + 1 < SS) {
        int ch = mt * 8 + (tid >> 5);
        int pos = (tid & 31) * 8;
        int row = pos >> 5, col = pos & 31;
        const float* xs = x + (((size_t)b * SS + t + 1) * CCH + ch) * PLANE + nt * 256 + pos;
        f16* zd = zwrite + (((size_t)b * ZP + nt * 8 + row + 1) * ZP + col + 1) * NIC + ch;
        #pragma unroll
        for (int k = 0; k < 8; ++k) zd[k * NIC] = (f16)xs[k];
    }

    __syncthreads();
    if (tid < 8) {
        float s = redbuf[0][tid] + redbuf[1][tid] + redbuf[2][tid] + redbuf[3][tid];
        int fm = tid >> 2;
        int hc = mt * 8 + fm * 4 + (tid & 3);
        // tid = fm*4 + q4  ->  hc = mt*8 + tid  (fm*4+q4 == tid)
        hc = mt * 8 + tid;
        atomicAdd(feat + ((size_t)b * SS + t) * 128 + hc, s * (1.f / 1024.f));
    }
}

// ---------------------------------------------------------------------------
// Head: feat -> relu(fc) -> offset/angle.
__global__ __launch_bounds__(128) void head_kernel(
    const float* __restrict__ feat, const float* __restrict__ fcw,
    const float* __restrict__ fcb, const float* __restrict__ fcow,
    const float* __restrict__ fcob, const float* __restrict__ fcaw,
    const float* __restrict__ fcab, float* __restrict__ out)
{
    __shared__ float sf[128];
    __shared__ float redo[2], reda[2];
    int bs = blockIdx.x;
    int c  = threadIdx.x;
    sf[c] = feat[(size_t)bs * 128 + c];
    __syncthreads();
    float a = fcb[c];
    #pragma unroll 8
    for (int k = 0; k < 128; ++k) a = fmaf(fcw[c * 128 + k], sf[k], a);
    a = fmaxf(a, 0.0f);
    float po = a * fcow[c], pa = a * fcaw[c];
    #pragma unroll
    for (int off = 32; off > 0; off >>= 1) {
        po += __shfl_down(po, off, 64);
        pa += __shfl_down(pa, off, 64);
    }
    if ((c & 63) == 0) { redo[c >> 6] = po; reda[c >> 6] = pa; }
    __syncthreads();
    if (c == 0) {
        out[bs]       = redo[0] + redo[1] + fcob[0];
        out[128 + bs] = reda[0] + reda[1] + fcab[0];
    }
}

// ---------------------------------------------------------------------------
extern "C" void kernel_launch(void* const* d_in, const int* in_sizes, int n_in,
                              void* d_out, int out_size, void* d_ws, size_t ws_size,
                              hipStream_t stream) {
    const float* x      = (const float*)d_in[0];
    const float* conv_w = (const float*)d_in[1];
    const float* conv_b = (const float*)d_in[2];
    const float* init_h = (const float*)d_in[3];
    const float* init_c = (const float*)d_in[4];
    const float* fc_w   = (const float*)d_in[5];
    const float* fc_b   = (const float*)d_in[6];
    const float* fco_w  = (const float*)d_in[7];
    const float* fco_b  = (const float*)d_in[8];
    const float* fca_w  = (const float*)d_in[9];
    const float* fca_b  = (const float*)d_in[10];

    unsigned char* wsb = (unsigned char*)d_ws;
    size_t off = 0;
    f16* wt = (f16*)(wsb + off);       off += (size_t)9 * 512 * 256 * 2;          // 2359296
    off = (off + 255) & ~(size_t)255;
    f16* zpad0 = (f16*)(wsb + off);    off += (size_t)BB * ZP * ZP * NIC * 2;     // 2367488
    off = (off + 255) & ~(size_t)255;
    f16* zpad1 = (f16*)(wsb + off);    off += (size_t)BB * ZP * ZP * NIC * 2;
    off = (off + 255) & ~(size_t)255;
    float* cst = (float*)(wsb + off);  off += (size_t)BB * 128 * PLANE * 4;       // 2097152
    off = (off + 255) & ~(size_t)255;
    float* feat = (float*)(wsb + off); off += (size_t)BB * SS * 128 * 4;          // 65536

    wprep_kernel<<<(9 * 512 * 256 + 255) / 256, 256, 0, stream>>>(conv_w, wt);
    init_kernel<<<BB * 34, 256, 0, stream>>>(x, init_h, init_c, zpad0, zpad1, cst, feat);

    f16* zb[2] = { zpad0, zpad1 };
    for (int t = 0; t < SS; ++t) {
        step_kernel<<<256, 256, 0, stream>>>(
            wt, zb[t & 1], zb[(t + 1) & 1], x, conv_b, cst, feat, t);
    }

    head_kernel<<<BB * SS, 128, 0, stream>>>(
        feat, fc_w, fc_b, fco_w, fco_b, fca_w, fca_b, (float*)d_out);
}

// Round 5
// 729.107 us; speedup vs baseline: 10.5259x; 1.0530x over previous
//
#include <hip/hip_runtime.h>
#include <math.h>

#define BB 4
#define SS 32
#define CCH 128
#define PLANE 1024
#define ZP 34
#define NOC 512
#define NIC 256

#define LDSA 18432            // A region: 1152 slots * 16B
#define LDSZ 21760            // Z region: 1360 slots * 16B
#define LDSB (LDSA + LDSZ)    // 40192 per buffer

typedef _Float16 f16;
typedef _Float16 f16x8 __attribute__((ext_vector_type(8)));
typedef float f32x4 __attribute__((ext_vector_type(4)));

__device__ __forceinline__ float sigmoidf_(float v) { return 1.0f / (1.0f + __expf(-v)); }
__device__ __forceinline__ float tanhf_(float v) { return 2.0f / (1.0f + __expf(-2.0f * v)) - 1.0f; }

__device__ __forceinline__ void gload16(const void* g, void* l) {
    __builtin_amdgcn_global_load_lds(
        (const __attribute__((address_space(1))) void*)g,
        (__attribute__((address_space(3))) void*)l, 16, 0, 0);
}

// ---------------------------------------------------------------------------
// Weight prep (once): conv_w [512][256][3][3] f32 -> wt [tap][oc'][ic] f16
// with oc' = hc*4 + g (gate-interleaved rows), src oc = g*128 + hc.
__global__ void wprep_kernel(const float* __restrict__ w, f16* __restrict__ wt) {
    int idx = blockIdx.x * 256 + threadIdx.x;
    if (idx >= 9 * 512 * 256) return;
    int ic  = idx & 255;
    int ocp = (idx >> 8) & 511;
    int tap = idx >> 17;
    int hc = ocp >> 2, g = ocp & 3;
    int oc = g * 128 + hc;
    wt[idx] = (f16)w[((size_t)(oc * 256 + ic)) * 9 + tap];
}

// ---------------------------------------------------------------------------
// Init: zpad0 interior = [x_0 ; init_h], borders of BOTH zpad buffers = 0,
// cst[b][hc][px] = init_c[hc], feat = 0.  grid = B*34, 256 threads (= channel).
__global__ __launch_bounds__(256) void init_kernel(
    const float* __restrict__ x, const float* __restrict__ ih,
    const float* __restrict__ icst, f16* __restrict__ zpad0,
    f16* __restrict__ zpad1, float* __restrict__ cst, float* __restrict__ feat)
{
    int bx = blockIdx.x;
    int b = bx / 34, y = bx % 34;
    int ch = threadIdx.x;
    f16* z0row = zpad0 + (((size_t)b * ZP + y) * ZP) * NIC;
    f16* z1row = zpad1 + (((size_t)b * ZP + y) * ZP) * NIC;
    bool border_y = (y == 0) | (y == 33);
    for (int xx = 0; xx < 34; ++xx) {
        bool border = border_y || xx == 0 || xx == 33;
        float v;
        if (border) v = 0.f;
        else if (ch < 128) v = x[((((size_t)b * SS + 0) * CCH + ch) * 32 + (y - 1)) * 32 + (xx - 1)];
        else v = ih[ch - 128];
        z0row[xx * NIC + ch] = (f16)v;
        if (border) z1row[xx * NIC + ch] = (f16)0.f;
    }
    if (y >= 1 && y <= 32 && ch < 128) {
        float cv = icst[ch];
        float* cr = cst + ((size_t)b * 128 + ch) * PLANE + (y - 1) * 32;
        for (int xx = 0; xx < 32; ++xx) cr[xx] = cv;
    }
    if (y == 33) {
        for (int k = 0; k < 16; ++k) feat[(size_t)b * 4096 + ch + k * 256] = 0.f;
    }
}

// ---------------------------------------------------------------------------
// Fused ConvLSTM step: full-K implicit GEMM (K = 9 taps x 256 ic) + LSTM
// pointwise + h->znext + x_{t+1}->znext + pooled mean.
// grid = 256: mt(16) | nt(4) | b(4).  Block: 32 oc' x 256 px, 256 thr,
// 4 waves 1(M)x4(N), wave tile 32x64.  Tap-pipelined LDS reads.
__global__ __launch_bounds__(256) void step_kernel(
    const f16* __restrict__ wt, const f16* __restrict__ zread,
    f16* __restrict__ zwrite, const float* __restrict__ x,
    const float* __restrict__ bias, float* __restrict__ cst,
    float* __restrict__ feat, int t)
{
    __shared__ unsigned char LDS[2 * LDSB];   // 80384 B
    __shared__ float redbuf[4][8];
    __shared__ f16 tbuf[256][8];              // 4 KB transpose bounce

    const int bid = blockIdx.x;
    const int mt = bid & 15;
    const int nt = (bid >> 4) & 3;
    const int b  = bid >> 6;
    const int tid = threadIdx.x;
    const int lane = tid & 63;
    const int wc = tid >> 6;          // wave = N-column 0..3

    // --- staging descriptors: 2512 slots (A 1152 + Z 1360), 10 rounds
    const f16* srcb[10];
    int soff[10];
    #pragma unroll
    for (int r = 0; r < 10; ++r) {
        int s = tid + r * 256;
        if (s < 1152) {                       // A: [tap][32 oc'][4 q]
            int tap = s >> 7, rem = s & 127;
            int p = rem >> 2, q = rem & 3;
            int qs = q ^ ((p >> 1) & 3);
            srcb[r] = wt + ((size_t)(tap * NOC + mt * 32 + p)) * NIC + qs * 8;
        } else {                              // Z: [340 px][4 q]
            int z = s - 1152;
            int p = z >> 2; if (p > 339) p = 339;
            int q = z & 3;
            int qs = q ^ ((p >> 1) & 3);
            int row = p / 34, xx = p - row * 34;
            srcb[r] = zread + (((size_t)b * ZP + nt * 8 + row) * ZP + xx) * NIC + qs * 8;
        }
        soff[r] = s * 16;
    }

    f32x4 acc[2][4];
    #pragma unroll
    for (int i = 0; i < 2; ++i)
        #pragma unroll
        for (int j = 0; j < 4; ++j) acc[i][j] = (f32x4){0.f, 0.f, 0.f, 0.f};

    auto stage = [&](int bufsel, int icc) {
        int ico = icc * 32;
        #pragma unroll
        for (int r = 0; r < 10; ++r) {
            if (r < 9 || tid < 208)
                gload16(srcb[r] + ico, LDS + bufsel * LDSB + soff[r]);
        }
    };

    const int q = lane >> 4;
    const int l15 = lane & 15;

    auto compute = [&](int bufsel) {
        const unsigned char* Ab = LDS + bufsel * LDSB;
        const unsigned char* Zb = Ab + LDSA;
        auto ldA = [&](int tap, int fm) -> f16x8 {
            int p = fm * 16 + l15;
            return *(const f16x8*)(Ab + (tap * 128 + p * 4 + (q ^ ((p >> 1) & 3))) * 16);
        };
        auto ldB = [&](int tap, int fn) -> f16x8 {
            int dy = tap / 3, dx = tap - dy * 3;
            int n = wc * 64 + fn * 16 + l15;
            int p = ((n >> 5) + dy) * 34 + (n & 31) + dx;
            return *(const f16x8*)(Zb + (p * 4 + (q ^ ((p >> 1) & 3))) * 16);
        };
        f16x8 a0 = ldA(0, 0), a1 = ldA(0, 1);
        f16x8 b0 = ldB(0, 0), b1 = ldB(0, 1), b2 = ldB(0, 2), b3 = ldB(0, 3);
        #pragma unroll
        for (int tap = 0; tap < 9; ++tap) {
            f16x8 na0, na1, nb0, nb1, nb2, nb3;
            if (tap < 8) {
                na0 = ldA(tap + 1, 0); na1 = ldA(tap + 1, 1);
                nb0 = ldB(tap + 1, 0); nb1 = ldB(tap + 1, 1);
                nb2 = ldB(tap + 1, 2); nb3 = ldB(tap + 1, 3);
            } else {
                na0 = a0; na1 = a1; nb0 = b0; nb1 = b1; nb2 = b2; nb3 = b3;
            }
            acc[0][0] = __builtin_amdgcn_mfma_f32_16x16x32_f16(a0, b0, acc[0][0], 0, 0, 0);
            acc[1][0] = __builtin_amdgcn_mfma_f32_16x16x32_f16(a1, b0, acc[1][0], 0, 0, 0);
            acc[0][1] = __builtin_amdgcn_mfma_f32_16x16x32_f16(a0, b1, acc[0][1], 0, 0, 0);
            acc[1][1] = __builtin_amdgcn_mfma_f32_16x16x32_f16(a1, b1, acc[1][1], 0, 0, 0);
            acc[0][2] = __builtin_amdgcn_mfma_f32_16x16x32_f16(a0, b2, acc[0][2], 0, 0, 0);
            acc[1][2] = __builtin_amdgcn_mfma_f32_16x16x32_f16(a1, b2, acc[1][2], 0, 0, 0);
            acc[0][3] = __builtin_amdgcn_mfma_f32_16x16x32_f16(a0, b3, acc[0][3], 0, 0, 0);
            acc[1][3] = __builtin_amdgcn_mfma_f32_16x16x32_f16(a1, b3, acc[1][3], 0, 0, 0);
            a0 = na0; a1 = na1; b0 = nb0; b1 = nb1; b2 = nb2; b3 = nb3;
        }
    };

    stage(0, 0);
    #pragma unroll
    for (int icc = 0; icc < 8; ++icc) {
        if (icc < 7) stage((icc + 1) & 1, icc + 1);
        if (icc < 7) asm volatile("s_waitcnt vmcnt(10)" ::: "memory");
        else         asm volatile("s_waitcnt vmcnt(0)" ::: "memory");
        __builtin_amdgcn_s_barrier();
        asm volatile("" ::: "memory");
        compute(icc & 1);
        asm volatile("" ::: "memory");
        __builtin_amdgcn_s_barrier();
    }

    // ---- fused LSTM pointwise epilogue (lane holds i,f,o,g in acc.xyzw) ----
    float psum[2];
    #pragma unroll
    for (int fm = 0; fm < 2; ++fm) {
        const int hcl = fm * 4 + q;                 // 0..7 within block
        const int hc = mt * 8 + hcl;
        const float bi = bias[hc], bff = bias[128 + hc];
        const float bo = bias[256 + hc], bg = bias[384 + hc];
        psum[fm] = 0.f;
        #pragma unroll
        for (int fn = 0; fn < 4; ++fn) {
            int pxloc = wc * 64 + fn * 16 + l15;    // 0..255 within nt tile
            f32x4 a = acc[fm][fn];
            float iv = sigmoidf_(a.x + bi);
            float fv = sigmoidf_(a.y + bff);
            float ov = sigmoidf_(a.z + bo);
            float gv = tanhf_(a.w + bg);
            size_t co = ((size_t)b * 128 + hc) * PLANE + nt * 256 + pxloc;
            float cp = cst[co];
            float cn = fv * cp + iv * gv;
            float hn = ov * tanhf_(cn);
            cst[co] = cn;
            tbuf[pxloc][hcl] = (f16)hn;
            psum[fm] += hn;
        }
    }
    #pragma unroll
    for (int m = 1; m < 16; m <<= 1) {
        psum[0] += __shfl_xor(psum[0], m, 64);
        psum[1] += __shfl_xor(psum[1], m, 64);
    }
    if (l15 == 0) {
        redbuf[wc][q]     = psum[0];
        redbuf[wc][4 + q] = psum[1];
    }
    __syncthreads();

    // coalesced h write: thread tid owns pixel nt*256+tid, 8 channels = 16B
    {
        f16x8 v = *(const f16x8*)tbuf[tid];
        int row = tid >> 5, col = tid & 31;
        *(f16x8*)(zwrite + (((size_t)b * ZP + nt * 8 + row + 1) * ZP + col + 1) * NIC
                  + 128 + mt * 8) = v;
    }
    if (tid < 8) {
        float s = redbuf[0][tid] + redbuf[1][tid] + redbuf[2][tid] + redbuf[3][tid];
        atomicAdd(feat + ((size_t)b * SS + t) * 128 + mt * 8 + tid, s * (1.f / 1024.f));
    }

    // ---- stage x_{t+1} into znext (channels mt*8..mt*8+7), coalesced ----
    if (t + 1 < SS) {
        __syncthreads();
        int ch = tid >> 5;                 // 0..7
        int pos = (tid & 31) * 8;          // 8 consecutive px
        const float* xs = x + (((size_t)b * SS + t + 1) * CCH + mt * 8 + ch) * PLANE
                          + nt * 256 + pos;
        float4 v0 = *(const float4*)xs;
        float4 v1 = *(const float4*)(xs + 4);
        tbuf[pos + 0][ch] = (f16)v0.x; tbuf[pos + 1][ch] = (f16)v0.y;
        tbuf[pos + 2][ch] = (f16)v0.z; tbuf[pos + 3][ch] = (f16)v0.w;
        tbuf[pos + 4][ch] = (f16)v1.x; tbuf[pos + 5][ch] = (f16)v1.y;
        tbuf[pos + 6][ch] = (f16)v1.z; tbuf[pos + 7][ch] = (f16)v1.w;
        __syncthreads();
        f16x8 v = *(const f16x8*)tbuf[tid];
        int row = tid >> 5, col = tid & 31;
        *(f16x8*)(zwrite + (((size_t)b * ZP + nt * 8 + row + 1) * ZP + col + 1) * NIC
                  + mt * 8) = v;
    }
}

// ---------------------------------------------------------------------------
// Head: feat -> relu(fc) -> offset/angle.
__global__ __launch_bounds__(128) void head_kernel(
    const float* __restrict__ feat, const float* __restrict__ fcw,
    const float* __restrict__ fcb, const float* __restrict__ fcow,
    const float* __restrict__ fcob, const float* __restrict__ fcaw,
    const float* __restrict__ fcab, float* __restrict__ out)
{
    __shared__ float sf[128];
    __shared__ float redo[2], reda[2];
    int bs = blockIdx.x;
    int c  = threadIdx.x;
    sf[c] = feat[(size_t)bs * 128 + c];
    __syncthreads();
    float a = fcb[c];
    #pragma unroll 8
    for (int k = 0; k < 128; ++k) a = fmaf(fcw[c * 128 + k], sf[k], a);
    a = fmaxf(a, 0.0f);
    float po = a * fcow[c], pa = a * fcaw[c];
    #pragma unroll
    for (int off = 32; off > 0; off >>= 1) {
        po += __shfl_down(po, off, 64);
        pa += __shfl_down(pa, off, 64);
    }
    if ((c & 63) == 0) { redo[c >> 6] = po; reda[c >> 6] = pa; }
    __syncthreads();
    if (c == 0) {
        out[bs]       = redo[0] + redo[1] + fcob[0];
        out[128 + bs] = reda[0] + reda[1] + fcab[0];
    }
}

// ---------------------------------------------------------------------------
extern "C" void kernel_launch(void* const* d_in, const int* in_sizes, int n_in,
                              void* d_out, int out_size, void* d_ws, size_t ws_size,
                              hipStream_t stream) {
    const float* x      = (const float*)d_in[0];
    const float* conv_w = (const float*)d_in[1];
    const float* conv_b = (const float*)d_in[2];
    const float* init_h = (const float*)d_in[3];
    const float* init_c = (const float*)d_in[4];
    const float* fc_w   = (const float*)d_in[5];
    const float* fc_b   = (const float*)d_in[6];
    const float* fco_w  = (const float*)d_in[7];
    const float* fco_b  = (const float*)d_in[8];
    const float* fca_w  = (const float*)d_in[9];
    const float* fca_b  = (const float*)d_in[10];

    unsigned char* wsb = (unsigned char*)d_ws;
    size_t off = 0;
    f16* wt = (f16*)(wsb + off);       off += (size_t)9 * 512 * 256 * 2;
    off = (off + 255) & ~(size_t)255;
    f16* zpad0 = (f16*)(wsb + off);    off += (size_t)BB * ZP * ZP * NIC * 2;
    off = (off + 255) & ~(size_t)255;
    f16* zpad1 = (f16*)(wsb + off);    off += (size_t)BB * ZP * ZP * NIC * 2;
    off = (off + 255) & ~(size_t)255;
    float* cst = (float*)(wsb + off);  off += (size_t)BB * 128 * PLANE * 4;
    off = (off + 255) & ~(size_t)255;
    float* feat = (float*)(wsb + off); off += (size_t)BB * SS * 128 * 4;

    wprep_kernel<<<(9 * 512 * 256 + 255) / 256, 256, 0, stream>>>(conv_w, wt);
    init_kernel<<<BB * 34, 256, 0, stream>>>(x, init_h, init_c, zpad0, zpad1, cst, feat);

    f16* zb[2] = { zpad0, zpad1 };
    for (int t = 0; t < SS; ++t) {
        step_kernel<<<256, 256, 0, stream>>>(
            wt, zb[t & 1], zb[(t + 1) & 1], x, conv_b, cst, feat, t);
    }

    head_kernel<<<BB * SS, 128, 0, stream>>>(
        feat, fc_w, fc_b, fco_w, fco_b, fca_w, fca_b, (float*)d_out);
}